// Round 3
// baseline (319.230 us; speedup 1.0000x reference)
//
#include <hip/hip_runtime.h>
#include <stdint.h>
#include <stddef.h>

// RBF kernel: out[i][j] = exp(-max(||x_i||^2 + ||x1_j||^2 - 2*x_i.x1_j, 0) / 1.0)
// N = M = 8192, K = 512, fp32 in/out.
//
// Round 3: same MX-fp8 (e4m3, unit scales) GEMM as round 2, with occupancy
// fixes: launch_bounds(256,3) + unroll-1 K-loop + epilogue operands loaded
// after the loop (round 2 likely blew past 256 VGPR -> 1 block/CU, exposing
// every barrier drain). Nontemporal output stores keep the 268 MB stream out
// of L2 (which holds the 8 MB fp8 inputs). Precast uses HW v_cvt_pk_fp8_f32.

#define NROWS 8192
#define DIMK  512
#define BM    128
#define BN    128
#define BKB   128              // K-bytes (= elements) per fp8 tile
#define KT    (DIMK / BKB)     // 4

typedef __bf16 bf16x8 __attribute__((ext_vector_type(8)));
typedef int    i32x8  __attribute__((ext_vector_type(8)));
typedef float  f32x4  __attribute__((ext_vector_type(4)));

#define AS1 __attribute__((address_space(1)))
#define AS3 __attribute__((address_space(3)))

__device__ __forceinline__ uint32_t f2bf(float f) {
    uint32_t u = __float_as_uint(f);
    return (u + 0x7FFFu + ((u >> 16) & 1u)) >> 16;
}

// pack 4 floats -> 4 e4m3 bytes via HW converter (RNE, saturating)
__device__ __forceinline__ uint32_t pk_fp8x4(float a, float b, float c, float d) {
    int w = __builtin_amdgcn_cvt_pk_fp8_f32(a, b, 0, false);   // bytes 0,1
    w     = __builtin_amdgcn_cvt_pk_fp8_f32(c, d, w, true);    // bytes 2,3
    return (uint32_t)w;
}

// ---------------------------------------------------------------- precast ---
// grid (2048, 2), block 256 = 4 waves; each wave: one 512-float row ->
// fp32 row norm (exact) + e4m3 cast. 32 B loads, 8 B stores, no divergence.
__global__ __launch_bounds__(256) void precast_fp8(
    const float* __restrict__ x, const float* __restrict__ x1,
    uint8_t* __restrict__ xf, uint8_t* __restrict__ x1f,
    float* __restrict__ xsq, float* __restrict__ x1sq)
{
    const int w    = threadIdx.x >> 6;
    const int lane = threadIdx.x & 63;
    const int row  = blockIdx.x * 4 + w;
    const float* src;
    uint8_t* dstb;
    float* dsts;
    if (blockIdx.y == 0) { src = x  + (size_t)row * DIMK; dstb = xf  + (size_t)row * DIMK; dsts = xsq  + row; }
    else                 { src = x1 + (size_t)row * DIMK; dstb = x1f + (size_t)row * DIMK; dsts = x1sq + row; }

    float4 v0 = ((const float4*)src)[lane * 2];
    float4 v1 = ((const float4*)src)[lane * 2 + 1];
    float s = v0.x * v0.x + v0.y * v0.y + v0.z * v0.z + v0.w * v0.w
            + v1.x * v1.x + v1.y * v1.y + v1.z * v1.z + v1.w * v1.w;

    uint2 p;
    p.x = pk_fp8x4(v0.x, v0.y, v0.z, v0.w);
    p.y = pk_fp8x4(v1.x, v1.y, v1.z, v1.w);
    ((uint2*)dstb)[lane] = p;

    #pragma unroll
    for (int off = 32; off > 0; off >>= 1) s += __shfl_down(s, off);
    if (lane == 0) *dsts = s;
}

// norms only (fallback path when ws can't hold the fp8 copies)
__global__ __launch_bounds__(256) void norms_only(
    const float* __restrict__ x, const float* __restrict__ x1,
    float* __restrict__ xsq, float* __restrict__ x1sq)
{
    const int row = blockIdx.x;
    const float* src = (blockIdx.y == 0) ? x + (size_t)row * DIMK : x1 + (size_t)row * DIMK;
    float* dsts      = (blockIdx.y == 0) ? xsq + row : x1sq + row;
    const int t = threadIdx.x;
    float2 v = ((const float2*)src)[t];
    float s = v.x * v.x + v.y * v.y;
    #pragma unroll
    for (int off = 32; off > 0; off >>= 1) s += __shfl_down(s, off);
    __shared__ float red[4];
    if ((t & 63) == 0) red[t >> 6] = s;
    __syncthreads();
    if (t == 0) *dsts = red[0] + red[1] + red[2] + red[3];
}

// ------------------------------------------------------- main GEMM (MX-fp8) ---
// block 256 = 4 waves in 2x2; each wave owns 64x64 output = 4x4 tiles of
// mfma_scale_f32_16x16x128_f8f6f4 with unit scales (e8m0 127 -> 2^0).
// Staging: global_load_lds width=16; thread t stages row t>>3, bytes
// (t&7)*16, call c adds 32 rows; LDS dest = t*16 + c*4096 (wave-uniform base
// + lane*16, as the HW requires). launch_bounds(256,3): cap VGPR ~168 so
// ~3 blocks/CU stay resident and hide the per-kt barrier drains (m114-style
// implicit overlap); round 2's register bloat is the suspected 80-us cause.
__global__ __launch_bounds__(256, 3) void rbf_mfma_mxfp8(
    const uint8_t* __restrict__ Xf, const uint8_t* __restrict__ X1f,
    const float* __restrict__ xsq, const float* __restrict__ x1sq,
    float* __restrict__ out)
{
    __shared__ uint8_t As[BM * BKB];   // 16 KB
    __shared__ uint8_t Bs[BN * BKB];   // 16 KB

    const int t    = threadIdx.x;
    const int bm   = blockIdx.x;
    const int bn   = blockIdx.y;
    const int lane = t & 63;
    const int w    = t >> 6;
    const int wm   = w >> 1;
    const int wn   = w & 1;

    const int srow = t >> 3;           // 0..31
    const int scol = (t & 7) * 16;     // byte col in 128B K-slab
    const uint8_t* gA = Xf  + (size_t)(bm * BM + srow) * DIMK + scol;
    const uint8_t* gB = X1f + (size_t)(bn * BN + srow) * DIMK + scol;
    uint8_t* lA = &As[t * 16];
    uint8_t* lB = &Bs[t * 16];

    f32x4 acc[4][4];
    #pragma unroll
    for (int i = 0; i < 4; ++i)
        #pragma unroll
        for (int j = 0; j < 4; ++j)
            acc[i][j] = f32x4{0.f, 0.f, 0.f, 0.f};

    // A-operand: A[m = lane&15][kbyte = (lane>>4)*32 + 0..31]; B same shape.
    const int lrow = lane & 15;
    const int kq   = (lane >> 4) * 32;
    int aoff[4], boff[4];
    #pragma unroll
    for (int i = 0; i < 4; ++i) {
        aoff[i] = (wm * 64 + i * 16 + lrow) * BKB + kq;
        boff[i] = (wn * 64 + i * 16 + lrow) * BKB + kq;
    }

    #pragma unroll 1                   // keep ONE iteration's frags live
    for (int kt = 0; kt < KT; ++kt) {
        const uint8_t* ga = gA + kt * BKB;
        const uint8_t* gb = gB + kt * BKB;
        #pragma unroll
        for (int c = 0; c < 4; ++c) {
            __builtin_amdgcn_global_load_lds((AS1 void*)(ga + (size_t)c * 32 * DIMK),
                                             (AS3 void*)(lA + c * 4096), 16, 0, 0);
            __builtin_amdgcn_global_load_lds((AS1 void*)(gb + (size_t)c * 32 * DIMK),
                                             (AS3 void*)(lB + c * 4096), 16, 0, 0);
        }
        __syncthreads();   // drain staging before fragment reads

        i32x8 af[4], bg[4];
        #pragma unroll
        for (int i = 0; i < 4; ++i) af[i] = *(const i32x8*)&As[aoff[i]];
        #pragma unroll
        for (int i = 0; i < 4; ++i) bg[i] = *(const i32x8*)&Bs[boff[i]];
        #pragma unroll
        for (int i = 0; i < 4; ++i)
            #pragma unroll
            for (int j = 0; j < 4; ++j)
                acc[i][j] = __builtin_amdgcn_mfma_scale_f32_16x16x128_f8f6f4(
                    af[i], bg[j], acc[i][j],
                    0, 0,                    // cbsz=0 (A fp8 e4m3), blgp=0 (B fp8 e4m3)
                    0, 0x7F7F7F7F,           // opselA, scaleA (e8m0 127 = 2^0)
                    0, 0x7F7F7F7F);          // opselB, scaleB
        if (kt + 1 < KT) __syncthreads();    // protect LDS before next stage
    }

    // epilogue: C/D layout col = lane&15, row = (lane>>4)*4 + reg.
    // Norm loads AFTER the K-loop (L2-hot, 32 KB total) — keeps them out of
    // the loop's live range.
    const int row0 = bm * BM + wm * 64 + (lane >> 4) * 4;
    const int col0 = bn * BN + wn * 64 + lrow;
    float xs[4][4], x1s[4];
    #pragma unroll
    for (int tm = 0; tm < 4; ++tm)
        #pragma unroll
        for (int r = 0; r < 4; ++r) xs[tm][r] = xsq[row0 + tm * 16 + r];
    #pragma unroll
    for (int tn = 0; tn < 4; ++tn) x1s[tn] = x1sq[col0 + tn * 16];

    #pragma unroll
    for (int tm = 0; tm < 4; ++tm)
        #pragma unroll
        for (int tn = 0; tn < 4; ++tn)
            #pragma unroll
            for (int r = 0; r < 4; ++r) {
                const int row = row0 + tm * 16 + r;
                const int col = col0 + tn * 16;
                float d = xs[tm][r] + x1s[tn] - 2.0f * acc[tm][tn][r];
                d = fmaxf(d, 0.0f);
                __builtin_nontemporal_store(__expf(-d), &out[(size_t)row * NROWS + col]);
            }
}

// Fallback GEMM (ws too small for fp8 copies): inline fp32->bf16 cast staging.
__global__ __launch_bounds__(256) void rbf_mfma_inline(
    const float* __restrict__ X, const float* __restrict__ X1,
    const float* __restrict__ xsq, const float* __restrict__ x1sq,
    float* __restrict__ out)
{
    __shared__ uint16_t As[BM * 32];
    __shared__ uint16_t Bs[BN * 32];

    const int t    = threadIdx.x;
    const int bm   = blockIdx.x;
    const int bn   = blockIdx.y;
    const int lane = t & 63;
    const int w    = t >> 6;
    const int wm   = w >> 1;
    const int wn   = w & 1;

    f32x4 acc[4][4];
    #pragma unroll
    for (int i = 0; i < 4; ++i)
        #pragma unroll
        for (int j = 0; j < 4; ++j)
            acc[i][j] = f32x4{0.f, 0.f, 0.f, 0.f};

    const int lrow = lane & 15;
    const int kq   = (lane >> 4) * 8;
    int aoff[4], boff[4];
    #pragma unroll
    for (int i = 0; i < 4; ++i) {
        aoff[i] = (wm * 64 + i * 16 + lrow) * 32 + kq;
        boff[i] = (wn * 64 + i * 16 + lrow) * 32 + kq;
    }

    #pragma unroll 1
    for (int kt = 0; kt < DIMK / 32; ++kt) {
        #pragma unroll
        for (int i = 0; i < 4; ++i) {
            const int g   = t + i * 256;
            const int row = g >> 3;
            const int c4  = (g & 7) * 4;
            float4 va = *(const float4*)&X [(size_t)(bm * BM + row) * DIMK + kt * 32 + c4];
            float4 vb = *(const float4*)&X1[(size_t)(bn * BN + row) * DIMK + kt * 32 + c4];
            uint2 pa, pb;
            pa.x = f2bf(va.x) | (f2bf(va.y) << 16);
            pa.y = f2bf(va.z) | (f2bf(va.w) << 16);
            pb.x = f2bf(vb.x) | (f2bf(vb.y) << 16);
            pb.y = f2bf(vb.z) | (f2bf(vb.w) << 16);
            *(uint2*)&As[g * 4] = pa;
            *(uint2*)&Bs[g * 4] = pb;
        }
        __syncthreads();

        bf16x8 af[4], bg[4];
        #pragma unroll
        for (int i = 0; i < 4; ++i) af[i] = *(const bf16x8*)&As[aoff[i]];
        #pragma unroll
        for (int i = 0; i < 4; ++i) bg[i] = *(const bf16x8*)&Bs[boff[i]];
        #pragma unroll
        for (int i = 0; i < 4; ++i)
            #pragma unroll
            for (int j = 0; j < 4; ++j)
                acc[i][j] = __builtin_amdgcn_mfma_f32_16x16x32_bf16(af[i], bg[j], acc[i][j], 0, 0, 0);
        __syncthreads();
    }

    const int row0 = bm * BM + wm * 64 + (lane >> 4) * 4;
    const int col0 = bn * BN + wn * 64 + lrow;
    float xs[4][4], x1s[4];
    #pragma unroll
    for (int tm = 0; tm < 4; ++tm)
        #pragma unroll
        for (int r = 0; r < 4; ++r) xs[tm][r] = xsq[row0 + tm * 16 + r];
    #pragma unroll
    for (int tn = 0; tn < 4; ++tn) x1s[tn] = x1sq[col0 + tn * 16];

    #pragma unroll
    for (int tm = 0; tm < 4; ++tm)
        #pragma unroll
        for (int tn = 0; tn < 4; ++tn)
            #pragma unroll
            for (int r = 0; r < 4; ++r) {
                const int row = row0 + tm * 16 + r;
                const int col = col0 + tn * 16;
                float d = xs[tm][r] + x1s[tn] - 2.0f * acc[tm][tn][r];
                d = fmaxf(d, 0.0f);
                out[(size_t)row * NROWS + col] = __expf(-d);
            }
}

// ------------------------------------------------------------------ launch ---
extern "C" void kernel_launch(void* const* d_in, const int* in_sizes, int n_in,
                              void* d_out, int out_size, void* d_ws, size_t ws_size,
                              hipStream_t stream)
{
    const float* x  = (const float*)d_in[0];
    const float* x1 = (const float*)d_in[1];
    float* out = (float*)d_out;

    const size_t f8_bytes  = (size_t)NROWS * DIMK;                       // 4 MB each
    const size_t need_full = 2 * f8_bytes + 2 * (size_t)NROWS * sizeof(float);

    dim3 gridG(NROWS / BM, NROWS / BN);   // 64 x 64 blocks

    if (ws_size >= need_full) {
        uint8_t* xf   = (uint8_t*)d_ws;
        uint8_t* x1f  = xf + f8_bytes;
        float*   xsq  = (float*)((char*)d_ws + 2 * f8_bytes);
        float*   x1sq = xsq + NROWS;
        precast_fp8<<<dim3(NROWS / 4, 2), 256, 0, stream>>>(x, x1, xf, x1f, xsq, x1sq);
        rbf_mfma_mxfp8<<<gridG, 256, 0, stream>>>(xf, x1f, xsq, x1sq, out);
    } else {
        float* xsq  = (float*)d_ws;       // 64 KB fallback
        float* x1sq = xsq + NROWS;
        norms_only<<<dim3(NROWS, 2), 256, 0, stream>>>(x, x1, xsq, x1sq);
        rbf_mfma_inline<<<gridG, 256, 0, stream>>>(x, x1, xsq, x1sq, out);
    }
}

// Round 4
// 308.191 us; speedup vs baseline: 1.0358x; 1.0358x over previous
//
#include <hip/hip_runtime.h>
#include <stdint.h>
#include <stddef.h>

// RBF kernel: out[i][j] = exp(-max(||x_i||^2 + ||x1_j||^2 - 2*x_i.x1_j, 0) / 1.0)
// N = M = 8192, K = 512, fp32 in/out.
//
// Round 4 = Round 2 base + XOR-swizzled LDS staging.
// Diagnosis: global_load_lds forces a row-major 128B-stride LDS tile; frag
// reads (16 rows x same 16B column) hit 4 banks -> 16-way conflicts ~5.7x
// (m136). 64KB/CU/kt of frag reads at ~2900cyc/kt x 4kt x 16 gens ~= 77us —
// matches the observed ~85us GEMM. Fix: thread t stages global chunk
// (t&7)^((t>>3)&7) so LDS chunk c of row r holds global chunk c^(r&7);
// frag reads become two 16B loads at chunks (2q)^s,(2q+1)^s (s=row&7) ->
// 8 distinct chunks per 16-lane quad -> full 32-bank spread, 2-way = free.

#define NROWS 8192
#define DIMK  512
#define BM    128
#define BN    128
#define BKB   128              // K-bytes (= elements) per fp8 tile
#define KT    (DIMK / BKB)     // 4

typedef __bf16 bf16x8 __attribute__((ext_vector_type(8)));
typedef int    i32x8  __attribute__((ext_vector_type(8)));
typedef int    i32x4  __attribute__((ext_vector_type(4)));
typedef float  f32x4  __attribute__((ext_vector_type(4)));

#define AS1 __attribute__((address_space(1)))
#define AS3 __attribute__((address_space(3)))

__device__ __forceinline__ uint32_t f2bf(float f) {
    uint32_t u = __float_as_uint(f);
    return (u + 0x7FFFu + ((u >> 16) & 1u)) >> 16;
}

// pack 4 floats -> 4 e4m3 bytes via HW converter (RNE, saturating)
__device__ __forceinline__ uint32_t pk_fp8x4(float a, float b, float c, float d) {
    int w = __builtin_amdgcn_cvt_pk_fp8_f32(a, b, 0, false);   // bytes 0,1
    w     = __builtin_amdgcn_cvt_pk_fp8_f32(c, d, w, true);    // bytes 2,3
    return (uint32_t)w;
}

// assemble a 32B MFMA fragment from two (possibly swapped) 16B LDS chunks
__device__ __forceinline__ i32x8 ld_frag(const uint8_t* base, int c_lo, int c_hi) {
    i32x4 lo = *(const i32x4*)(base + c_lo);
    i32x4 hi = *(const i32x4*)(base + c_hi);
    i32x8 r;
    r[0] = lo[0]; r[1] = lo[1]; r[2] = lo[2]; r[3] = lo[3];
    r[4] = hi[0]; r[5] = hi[1]; r[6] = hi[2]; r[7] = hi[3];
    return r;
}

// ---------------------------------------------------------------- precast ---
// grid (2048, 2), block 256 = 4 waves; each wave: one 512-float row ->
// fp32 row norm (exact) + e4m3 cast. 32 B loads, 8 B stores, no divergence.
__global__ __launch_bounds__(256) void precast_fp8(
    const float* __restrict__ x, const float* __restrict__ x1,
    uint8_t* __restrict__ xf, uint8_t* __restrict__ x1f,
    float* __restrict__ xsq, float* __restrict__ x1sq)
{
    const int w    = threadIdx.x >> 6;
    const int lane = threadIdx.x & 63;
    const int row  = blockIdx.x * 4 + w;
    const float* src;
    uint8_t* dstb;
    float* dsts;
    if (blockIdx.y == 0) { src = x  + (size_t)row * DIMK; dstb = xf  + (size_t)row * DIMK; dsts = xsq  + row; }
    else                 { src = x1 + (size_t)row * DIMK; dstb = x1f + (size_t)row * DIMK; dsts = x1sq + row; }

    float4 v0 = ((const float4*)src)[lane * 2];
    float4 v1 = ((const float4*)src)[lane * 2 + 1];
    float s = v0.x * v0.x + v0.y * v0.y + v0.z * v0.z + v0.w * v0.w
            + v1.x * v1.x + v1.y * v1.y + v1.z * v1.z + v1.w * v1.w;

    uint2 p;
    p.x = pk_fp8x4(v0.x, v0.y, v0.z, v0.w);
    p.y = pk_fp8x4(v1.x, v1.y, v1.z, v1.w);
    ((uint2*)dstb)[lane] = p;

    #pragma unroll
    for (int off = 32; off > 0; off >>= 1) s += __shfl_down(s, off);
    if (lane == 0) *dsts = s;
}

// norms only (fallback path when ws can't hold the fp8 copies)
__global__ __launch_bounds__(256) void norms_only(
    const float* __restrict__ x, const float* __restrict__ x1,
    float* __restrict__ xsq, float* __restrict__ x1sq)
{
    const int row = blockIdx.x;
    const float* src = (blockIdx.y == 0) ? x + (size_t)row * DIMK : x1 + (size_t)row * DIMK;
    float* dsts      = (blockIdx.y == 0) ? xsq + row : x1sq + row;
    const int t = threadIdx.x;
    float2 v = ((const float2*)src)[t];
    float s = v.x * v.x + v.y * v.y;
    #pragma unroll
    for (int off = 32; off > 0; off >>= 1) s += __shfl_down(s, off);
    __shared__ float red[4];
    if ((t & 63) == 0) red[t >> 6] = s;
    __syncthreads();
    if (t == 0) *dsts = red[0] + red[1] + red[2] + red[3];
}

// ------------------------------------------------------- main GEMM (MX-fp8) ---
// block 256 = 4 waves in 2x2; each wave owns 64x64 output = 4x4 tiles of
// mfma_scale_f32_16x16x128_f8f6f4 with unit scales (e8m0 127 -> 2^0).
// Staging: global_load_lds width=16; LDS dest forced to t*16 (+c*4096);
// thread t fetches global chunk (t&7)^((t>>3)&7) of row t>>3 (+32c) so the
// LDS tile is XOR-swizzled and frag reads spread across all 32 banks.
__global__ __launch_bounds__(256) void rbf_mfma_mxfp8(
    const uint8_t* __restrict__ Xf, const uint8_t* __restrict__ X1f,
    const float* __restrict__ xsq, const float* __restrict__ x1sq,
    float* __restrict__ out)
{
    __shared__ uint8_t As[BM * BKB];   // 16 KB
    __shared__ uint8_t Bs[BN * BKB];   // 16 KB

    const int t    = threadIdx.x;
    const int bm   = blockIdx.x;
    const int bn   = blockIdx.y;
    const int lane = t & 63;
    const int w    = t >> 6;
    const int wm   = w >> 1;
    const int wn   = w & 1;

    const int srow   = t >> 3;                       // 0..31
    const int schunk = (t & 7) ^ (srow & 7);         // swizzled global chunk
    const uint8_t* gA = Xf  + (size_t)(bm * BM + srow) * DIMK + schunk * 16;
    const uint8_t* gB = X1f + (size_t)(bn * BN + srow) * DIMK + schunk * 16;
    uint8_t* lA = &As[t * 16];                       // forced by HW rule
    uint8_t* lB = &Bs[t * 16];

    // epilogue operand prefetch (hidden under the K-loop)
    const int lrow = lane & 15;
    const int row0 = bm * BM + wm * 64 + (lane >> 4) * 4;
    const int col0 = bn * BN + wn * 64 + lrow;
    float xs[4][4], x1s[4];
    #pragma unroll
    for (int tm = 0; tm < 4; ++tm)
        #pragma unroll
        for (int r = 0; r < 4; ++r) xs[tm][r] = xsq[row0 + tm * 16 + r];
    #pragma unroll
    for (int tn = 0; tn < 4; ++tn) x1s[tn] = x1sq[col0 + tn * 16];

    f32x4 acc[4][4];
    #pragma unroll
    for (int i = 0; i < 4; ++i)
        #pragma unroll
        for (int j = 0; j < 4; ++j)
            acc[i][j] = f32x4{0.f, 0.f, 0.f, 0.f};

    // A-operand: A[m = lane&15][kbyte = q*32 + 0..31], q = lane>>4.
    // Swizzle: kbyte chunk 2q lives at LDS chunk (2q)^s, s = row&7 = lrow&7.
    const int q    = lane >> 4;
    const int s    = lrow & 7;
    const int c_lo = ((2 * q)     ^ s) * 16;
    const int c_hi = ((2 * q + 1) ^ s) * 16;
    int roff[4];
    #pragma unroll
    for (int i = 0; i < 4; ++i) roff[i] = (i * 16 + lrow) * BKB;   // wm/wn added below

    #pragma unroll
    for (int kt = 0; kt < KT; ++kt) {
        const uint8_t* ga = gA + kt * BKB;
        const uint8_t* gb = gB + kt * BKB;
        #pragma unroll
        for (int c = 0; c < 4; ++c) {
            __builtin_amdgcn_global_load_lds((AS1 void*)(ga + (size_t)c * 32 * DIMK),
                                             (AS3 void*)(lA + c * 4096), 16, 0, 0);
            __builtin_amdgcn_global_load_lds((AS1 void*)(gb + (size_t)c * 32 * DIMK),
                                             (AS3 void*)(lB + c * 4096), 16, 0, 0);
        }
        __syncthreads();   // drain staging before fragment reads

        i32x8 af[4], bg[4];
        #pragma unroll
        for (int i = 0; i < 4; ++i)
            af[i] = ld_frag(&As[wm * 64 * BKB + roff[i]], c_lo, c_hi);
        #pragma unroll
        for (int i = 0; i < 4; ++i)
            bg[i] = ld_frag(&Bs[wn * 64 * BKB + roff[i]], c_lo, c_hi);
        #pragma unroll
        for (int i = 0; i < 4; ++i)
            #pragma unroll
            for (int j = 0; j < 4; ++j)
                acc[i][j] = __builtin_amdgcn_mfma_scale_f32_16x16x128_f8f6f4(
                    af[i], bg[j], acc[i][j],
                    0, 0,                    // cbsz=0 (A fp8 e4m3), blgp=0 (B fp8 e4m3)
                    0, 0x7F7F7F7F,           // opselA, scaleA (e8m0 127 = 2^0)
                    0, 0x7F7F7F7F);          // opselB, scaleB
        __syncthreads();   // protect LDS before next stage
    }

    // epilogue: C/D layout col = lane&15, row = (lane>>4)*4 + reg
    #pragma unroll
    for (int tm = 0; tm < 4; ++tm)
        #pragma unroll
        for (int tn = 0; tn < 4; ++tn)
            #pragma unroll
            for (int r = 0; r < 4; ++r) {
                const int row = row0 + tm * 16 + r;
                const int col = col0 + tn * 16;
                float d = xs[tm][r] + x1s[tn] - 2.0f * acc[tm][tn][r];
                d = fmaxf(d, 0.0f);
                out[(size_t)row * NROWS + col] = __expf(-d);
            }
}

// Fallback GEMM (ws too small for fp8 copies): inline fp32->bf16 cast staging.
__global__ __launch_bounds__(256) void rbf_mfma_inline(
    const float* __restrict__ X, const float* __restrict__ X1,
    const float* __restrict__ xsq, const float* __restrict__ x1sq,
    float* __restrict__ out)
{
    __shared__ uint16_t As[BM * 32];
    __shared__ uint16_t Bs[BN * 32];

    const int t    = threadIdx.x;
    const int bm   = blockIdx.x;
    const int bn   = blockIdx.y;
    const int lane = t & 63;
    const int w    = t >> 6;
    const int wm   = w >> 1;
    const int wn   = w & 1;

    f32x4 acc[4][4];
    #pragma unroll
    for (int i = 0; i < 4; ++i)
        #pragma unroll
        for (int j = 0; j < 4; ++j)
            acc[i][j] = f32x4{0.f, 0.f, 0.f, 0.f};

    const int lrow = lane & 15;
    const int kq   = (lane >> 4) * 8;
    int aoff[4], boff[4];
    #pragma unroll
    for (int i = 0; i < 4; ++i) {
        aoff[i] = (wm * 64 + i * 16 + lrow) * 32 + kq;
        boff[i] = (wn * 64 + i * 16 + lrow) * 32 + kq;
    }

    #pragma unroll 1
    for (int kt = 0; kt < DIMK / 32; ++kt) {
        #pragma unroll
        for (int i = 0; i < 4; ++i) {
            const int g   = t + i * 256;
            const int row = g >> 3;
            const int c4  = (g & 7) * 4;
            float4 va = *(const float4*)&X [(size_t)(bm * BM + row) * DIMK + kt * 32 + c4];
            float4 vb = *(const float4*)&X1[(size_t)(bn * BN + row) * DIMK + kt * 32 + c4];
            uint2 pa, pb;
            pa.x = f2bf(va.x) | (f2bf(va.y) << 16);
            pa.y = f2bf(va.z) | (f2bf(va.w) << 16);
            pb.x = f2bf(vb.x) | (f2bf(vb.y) << 16);
            pb.y = f2bf(vb.z) | (f2bf(vb.w) << 16);
            *(uint2*)&As[g * 4] = pa;
            *(uint2*)&Bs[g * 4] = pb;
        }
        __syncthreads();

        bf16x8 af[4], bg[4];
        #pragma unroll
        for (int i = 0; i < 4; ++i) af[i] = *(const bf16x8*)&As[aoff[i]];
        #pragma unroll
        for (int i = 0; i < 4; ++i) bg[i] = *(const bf16x8*)&Bs[boff[i]];
        #pragma unroll
        for (int i = 0; i < 4; ++i)
            #pragma unroll
            for (int j = 0; j < 4; ++j)
                acc[i][j] = __builtin_amdgcn_mfma_f32_16x16x32_bf16(af[i], bg[j], acc[i][j], 0, 0, 0);
        __syncthreads();
    }

    const int row0 = bm * BM + wm * 64 + (lane >> 4) * 4;
    const int col0 = bn * BN + wn * 64 + lrow;
    float xs[4][4], x1s[4];
    #pragma unroll
    for (int tm = 0; tm < 4; ++tm)
        #pragma unroll
        for (int r = 0; r < 4; ++r) xs[tm][r] = xsq[row0 + tm * 16 + r];
    #pragma unroll
    for (int tn = 0; tn < 4; ++tn) x1s[tn] = x1sq[col0 + tn * 16];

    #pragma unroll
    for (int tm = 0; tm < 4; ++tm)
        #pragma unroll
        for (int tn = 0; tn < 4; ++tn)
            #pragma unroll
            for (int r = 0; r < 4; ++r) {
                const int row = row0 + tm * 16 + r;
                const int col = col0 + tn * 16;
                float d = xs[tm][r] + x1s[tn] - 2.0f * acc[tm][tn][r];
                d = fmaxf(d, 0.0f);
                out[(size_t)row * NROWS + col] = __expf(-d);
            }
}

// ------------------------------------------------------------------ launch ---
extern "C" void kernel_launch(void* const* d_in, const int* in_sizes, int n_in,
                              void* d_out, int out_size, void* d_ws, size_t ws_size,
                              hipStream_t stream)
{
    const float* x  = (const float*)d_in[0];
    const float* x1 = (const float*)d_in[1];
    float* out = (float*)d_out;

    const size_t f8_bytes  = (size_t)NROWS * DIMK;                       // 4 MB each
    const size_t need_full = 2 * f8_bytes + 2 * (size_t)NROWS * sizeof(float);

    dim3 gridG(NROWS / BM, NROWS / BN);   // 64 x 64 blocks

    if (ws_size >= need_full) {
        uint8_t* xf   = (uint8_t*)d_ws;
        uint8_t* x1f  = xf + f8_bytes;
        float*   xsq  = (float*)((char*)d_ws + 2 * f8_bytes);
        float*   x1sq = xsq + NROWS;
        precast_fp8<<<dim3(NROWS / 4, 2), 256, 0, stream>>>(x, x1, xf, x1f, xsq, x1sq);
        rbf_mfma_mxfp8<<<gridG, 256, 0, stream>>>(xf, x1f, xsq, x1sq, out);
    } else {
        float* xsq  = (float*)d_ws;       // 64 KB fallback
        float* x1sq = xsq + NROWS;
        norms_only<<<dim3(NROWS, 2), 256, 0, stream>>>(x, x1, xsq, x1sq);
        rbf_mfma_inline<<<gridG, 256, 0, stream>>>(x, x1, xsq, x1sq, out);
    }
}

// Round 5
// 304.293 us; speedup vs baseline: 1.0491x; 1.0128x over previous
//
#include <hip/hip_runtime.h>
#include <stdint.h>
#include <stddef.h>

// RBF kernel: out[i][j] = exp(-max(||x_i||^2 + ||x1_j||^2 - 2*x_i.x1_j, 0) / 1.0)
// N = M = 8192, K = 512, fp32 in/out.
//
// Round 5 = Round 4 (MX-fp8 + XOR-swizzled staging) + AITER-style pipelined
// K-loop: double-buffered LDS with raw s_barrier + explicit s_waitcnt
// vmcnt(8) so tile kt+2's global_load_lds stays in flight across barriers
// (never vmcnt(0) until the last tile). This removes the per-kt L2-latency
// drain the __syncthreads structure exposes (m97's ~20% stall; worse here
// since fp8 halves compute per barrier).

#define NROWS 8192
#define DIMK  512
#define BM    128
#define BN    128
#define BKB   128              // K-bytes (= elements) per fp8 tile
#define KT    (DIMK / BKB)     // 4

typedef __bf16 bf16x8 __attribute__((ext_vector_type(8)));
typedef int    i32x8  __attribute__((ext_vector_type(8)));
typedef int    i32x4  __attribute__((ext_vector_type(4)));
typedef float  f32x4  __attribute__((ext_vector_type(4)));

#define AS1 __attribute__((address_space(1)))
#define AS3 __attribute__((address_space(3)))

// raw waits/barrier — keep prefetch DMA in flight across barriers
#define WAITV(n) asm volatile("s_waitcnt vmcnt(" #n ")" ::: "memory")
#define WAITL()  asm volatile("s_waitcnt lgkmcnt(0)" ::: "memory")
#define BAR()    asm volatile("s_barrier" ::: "memory")

__device__ __forceinline__ uint32_t f2bf(float f) {
    uint32_t u = __float_as_uint(f);
    return (u + 0x7FFFu + ((u >> 16) & 1u)) >> 16;
}

// pack 4 floats -> 4 e4m3 bytes via HW converter (RNE, saturating)
__device__ __forceinline__ uint32_t pk_fp8x4(float a, float b, float c, float d) {
    int w = __builtin_amdgcn_cvt_pk_fp8_f32(a, b, 0, false);   // bytes 0,1
    w     = __builtin_amdgcn_cvt_pk_fp8_f32(c, d, w, true);    // bytes 2,3
    return (uint32_t)w;
}

// assemble a 32B MFMA fragment from two (swizzle-permuted) 16B LDS chunks
__device__ __forceinline__ i32x8 ld_frag(const uint8_t* base, int c_lo, int c_hi) {
    i32x4 lo = *(const i32x4*)(base + c_lo);
    i32x4 hi = *(const i32x4*)(base + c_hi);
    i32x8 r;
    r[0] = lo[0]; r[1] = lo[1]; r[2] = lo[2]; r[3] = lo[3];
    r[4] = hi[0]; r[5] = hi[1]; r[6] = hi[2]; r[7] = hi[3];
    return r;
}

// ---------------------------------------------------------------- precast ---
__global__ __launch_bounds__(256) void precast_fp8(
    const float* __restrict__ x, const float* __restrict__ x1,
    uint8_t* __restrict__ xf, uint8_t* __restrict__ x1f,
    float* __restrict__ xsq, float* __restrict__ x1sq)
{
    const int w    = threadIdx.x >> 6;
    const int lane = threadIdx.x & 63;
    const int row  = blockIdx.x * 4 + w;
    const float* src;
    uint8_t* dstb;
    float* dsts;
    if (blockIdx.y == 0) { src = x  + (size_t)row * DIMK; dstb = xf  + (size_t)row * DIMK; dsts = xsq  + row; }
    else                 { src = x1 + (size_t)row * DIMK; dstb = x1f + (size_t)row * DIMK; dsts = x1sq + row; }

    float4 v0 = ((const float4*)src)[lane * 2];
    float4 v1 = ((const float4*)src)[lane * 2 + 1];
    float s = v0.x * v0.x + v0.y * v0.y + v0.z * v0.z + v0.w * v0.w
            + v1.x * v1.x + v1.y * v1.y + v1.z * v1.z + v1.w * v1.w;

    uint2 p;
    p.x = pk_fp8x4(v0.x, v0.y, v0.z, v0.w);
    p.y = pk_fp8x4(v1.x, v1.y, v1.z, v1.w);
    ((uint2*)dstb)[lane] = p;

    #pragma unroll
    for (int off = 32; off > 0; off >>= 1) s += __shfl_down(s, off);
    if (lane == 0) *dsts = s;
}

// norms only (fallback path)
__global__ __launch_bounds__(256) void norms_only(
    const float* __restrict__ x, const float* __restrict__ x1,
    float* __restrict__ xsq, float* __restrict__ x1sq)
{
    const int row = blockIdx.x;
    const float* src = (blockIdx.y == 0) ? x + (size_t)row * DIMK : x1 + (size_t)row * DIMK;
    float* dsts      = (blockIdx.y == 0) ? xsq + row : x1sq + row;
    const int t = threadIdx.x;
    float2 v = ((const float2*)src)[t];
    float s = v.x * v.x + v.y * v.y;
    #pragma unroll
    for (int off = 32; off > 0; off >>= 1) s += __shfl_down(s, off);
    __shared__ float red[4];
    if ((t & 63) == 0) red[t >> 6] = s;
    __syncthreads();
    if (t == 0) *dsts = red[0] + red[1] + red[2] + red[3];
}

// ------------------------------------------- main GEMM (MX-fp8, pipelined) ---
// Wait ladder (8 DMA loads per stage, vmcnt completes in order — m135):
//   prologue: stage(0->buf0), stage(1->buf1)            [16 outstanding]
//   kt=0: vmcnt(8)+bar (tile0 ready everywhere) | reads | lgkm+bar | stage(2->buf0) | mfma
//   kt=1: vmcnt(8)+bar (tile1)                  | reads | lgkm+bar | stage(3->buf1) | mfma
//   kt=2: vmcnt(8)+bar (tile2)                  | reads |                           | mfma
//   kt=3: vmcnt(0)+bar (tile3)                  | reads |                           | mfma
// Epilogue vmem (norm loads, stores) strictly after the last wait so the
// vmcnt bookkeeping above stays exact.
__global__ __launch_bounds__(256) void rbf_mfma_mxfp8(
    const uint8_t* __restrict__ Xf, const uint8_t* __restrict__ X1f,
    const float* __restrict__ xsq, const float* __restrict__ x1sq,
    float* __restrict__ out)
{
    __shared__ uint8_t As[2][BM * BKB];   // 2 x 16 KB
    __shared__ uint8_t Bs[2][BN * BKB];   // 2 x 16 KB

    const int t    = threadIdx.x;
    const int bm   = blockIdx.x;
    const int bn   = blockIdx.y;
    const int lane = t & 63;
    const int w    = t >> 6;
    const int wm   = w >> 1;
    const int wn   = w & 1;

    const int srow   = t >> 3;                       // 0..31
    const int schunk = (t & 7) ^ (srow & 7);         // XOR-swizzled global chunk
    const uint8_t* gA = Xf  + (size_t)(bm * BM + srow) * DIMK + schunk * 16;
    const uint8_t* gB = X1f + (size_t)(bn * BN + srow) * DIMK + schunk * 16;

    f32x4 acc[4][4];
    #pragma unroll
    for (int i = 0; i < 4; ++i)
        #pragma unroll
        for (int j = 0; j < 4; ++j)
            acc[i][j] = f32x4{0.f, 0.f, 0.f, 0.f};

    // A-operand: A[m = lane&15][kbyte = q*32 + 0..31], q = lane>>4.
    // Swizzle: kbyte chunk c of row r lives at LDS chunk c^(r&7).
    const int lrow = lane & 15;
    const int q    = lane >> 4;
    const int s    = lrow & 7;
    const int c_lo = ((2 * q)     ^ s) * 16;
    const int c_hi = ((2 * q + 1) ^ s) * 16;
    int roff[4];
    #pragma unroll
    for (int i = 0; i < 4; ++i) roff[i] = (i * 16 + lrow) * BKB;

    // stage tile kt into buffer b: 8 global_load_lds dwordx4 per thread
    auto stage = [&](int kt, int b) {
        const uint8_t* ga = gA + kt * BKB;
        const uint8_t* gb = gB + kt * BKB;
        uint8_t* la = &As[b][t * 16];
        uint8_t* lb = &Bs[b][t * 16];
        #pragma unroll
        for (int c = 0; c < 4; ++c) {
            __builtin_amdgcn_global_load_lds((AS1 void*)(ga + (size_t)c * 32 * DIMK),
                                             (AS3 void*)(la + c * 4096), 16, 0, 0);
            __builtin_amdgcn_global_load_lds((AS1 void*)(gb + (size_t)c * 32 * DIMK),
                                             (AS3 void*)(lb + c * 4096), 16, 0, 0);
        }
    };

    auto read_frags = [&](int b, i32x8* af, i32x8* bg) {
        #pragma unroll
        for (int i = 0; i < 4; ++i)
            af[i] = ld_frag(&As[b][wm * 64 * BKB + roff[i]], c_lo, c_hi);
        #pragma unroll
        for (int i = 0; i < 4; ++i)
            bg[i] = ld_frag(&Bs[b][wn * 64 * BKB + roff[i]], c_lo, c_hi);
    };

    auto do_mfma = [&](const i32x8* af, const i32x8* bg) {
        #pragma unroll
        for (int i = 0; i < 4; ++i)
            #pragma unroll
            for (int j = 0; j < 4; ++j)
                acc[i][j] = __builtin_amdgcn_mfma_scale_f32_16x16x128_f8f6f4(
                    af[i], bg[j], acc[i][j],
                    0, 0,                    // cbsz=0 (A fp8 e4m3), blgp=0 (B fp8 e4m3)
                    0, 0x7F7F7F7F,           // opselA, scaleA (e8m0 127 = 2^0)
                    0, 0x7F7F7F7F);          // opselB, scaleB
    };

    i32x8 af[4], bg[4];

    stage(0, 0);
    stage(1, 1);                           // 16 outstanding

    // kt = 0
    WAITV(8); BAR();                       // tile0 ready on all waves
    read_frags(0, af, bg);
    WAITL(); BAR();                        // buf0 free to overwrite
    stage(2, 0);                           // 16 outstanding
    do_mfma(af, bg);

    // kt = 1
    WAITV(8); BAR();                       // tile1 ready
    read_frags(1, af, bg);
    WAITL(); BAR();                        // buf1 free to overwrite
    stage(3, 1);                           // 16 outstanding
    do_mfma(af, bg);

    // kt = 2
    WAITV(8); BAR();                       // tile2 ready
    read_frags(0, af, bg);
    do_mfma(af, bg);

    // kt = 3
    WAITV(0); BAR();                       // tile3 ready
    read_frags(1, af, bg);
    do_mfma(af, bg);

    // epilogue: C/D layout col = lane&15, row = (lane>>4)*4 + reg
    const int row0 = bm * BM + wm * 64 + (lane >> 4) * 4;
    const int col0 = bn * BN + wn * 64 + lrow;
    float xs[4][4], x1s[4];
    #pragma unroll
    for (int tm = 0; tm < 4; ++tm)
        #pragma unroll
        for (int r = 0; r < 4; ++r) xs[tm][r] = xsq[row0 + tm * 16 + r];
    #pragma unroll
    for (int tn = 0; tn < 4; ++tn) x1s[tn] = x1sq[col0 + tn * 16];

    #pragma unroll
    for (int tm = 0; tm < 4; ++tm)
        #pragma unroll
        for (int tn = 0; tn < 4; ++tn)
            #pragma unroll
            for (int r = 0; r < 4; ++r) {
                const int row = row0 + tm * 16 + r;
                const int col = col0 + tn * 16;
                float d = xs[tm][r] + x1s[tn] - 2.0f * acc[tm][tn][r];
                d = fmaxf(d, 0.0f);
                out[(size_t)row * NROWS + col] = __expf(-d);
            }
}

// Fallback GEMM (ws too small for fp8 copies): inline fp32->bf16 cast staging.
__global__ __launch_bounds__(256) void rbf_mfma_inline(
    const float* __restrict__ X, const float* __restrict__ X1,
    const float* __restrict__ xsq, const float* __restrict__ x1sq,
    float* __restrict__ out)
{
    __shared__ uint16_t As[BM * 32];
    __shared__ uint16_t Bs[BN * 32];

    const int t    = threadIdx.x;
    const int bm   = blockIdx.x;
    const int bn   = blockIdx.y;
    const int lane = t & 63;
    const int w    = t >> 6;
    const int wm   = w >> 1;
    const int wn   = w & 1;

    f32x4 acc[4][4];
    #pragma unroll
    for (int i = 0; i < 4; ++i)
        #pragma unroll
        for (int j = 0; j < 4; ++j)
            acc[i][j] = f32x4{0.f, 0.f, 0.f, 0.f};

    const int lrow = lane & 15;
    const int kq   = (lane >> 4) * 8;
    int aoff[4], boff[4];
    #pragma unroll
    for (int i = 0; i < 4; ++i) {
        aoff[i] = (wm * 64 + i * 16 + lrow) * 32 + kq;
        boff[i] = (wn * 64 + i * 16 + lrow) * 32 + kq;
    }

    #pragma unroll 1
    for (int kt = 0; kt < DIMK / 32; ++kt) {
        #pragma unroll
        for (int i = 0; i < 4; ++i) {
            const int g   = t + i * 256;
            const int row = g >> 3;
            const int c4  = (g & 7) * 4;
            float4 va = *(const float4*)&X [(size_t)(bm * BM + row) * DIMK + kt * 32 + c4];
            float4 vb = *(const float4*)&X1[(size_t)(bn * BN + row) * DIMK + kt * 32 + c4];
            uint2 pa, pb;
            pa.x = f2bf(va.x) | (f2bf(va.y) << 16);
            pa.y = f2bf(va.z) | (f2bf(va.w) << 16);
            pb.x = f2bf(vb.x) | (f2bf(vb.y) << 16);
            pb.y = f2bf(vb.z) | (f2bf(vb.w) << 16);
            *(uint2*)&As[g * 4] = pa;
            *(uint2*)&Bs[g * 4] = pb;
        }
        __syncthreads();

        bf16x8 af[4], bg[4];
        #pragma unroll
        for (int i = 0; i < 4; ++i) af[i] = *(const bf16x8*)&As[aoff[i]];
        #pragma unroll
        for (int i = 0; i < 4; ++i) bg[i] = *(const bf16x8*)&Bs[boff[i]];
        #pragma unroll
        for (int i = 0; i < 4; ++i)
            #pragma unroll
            for (int j = 0; j < 4; ++j)
                acc[i][j] = __builtin_amdgcn_mfma_f32_16x16x32_bf16(af[i], bg[j], acc[i][j], 0, 0, 0);
        __syncthreads();
    }

    const int row0 = bm * BM + wm * 64 + (lane >> 4) * 4;
    const int col0 = bn * BN + wn * 64 + lrow;
    float xs[4][4], x1s[4];
    #pragma unroll
    for (int tm = 0; tm < 4; ++tm)
        #pragma unroll
        for (int r = 0; r < 4; ++r) xs[tm][r] = xsq[row0 + tm * 16 + r];
    #pragma unroll
    for (int tn = 0; tn < 4; ++tn) x1s[tn] = x1sq[col0 + tn * 16];

    #pragma unroll
    for (int tm = 0; tm < 4; ++tm)
        #pragma unroll
        for (int tn = 0; tn < 4; ++tn)
            #pragma unroll
            for (int r = 0; r < 4; ++r) {
                const int row = row0 + tm * 16 + r;
                const int col = col0 + tn * 16;
                float d = xs[tm][r] + x1s[tn] - 2.0f * acc[tm][tn][r];
                d = fmaxf(d, 0.0f);
                out[(size_t)row * NROWS + col] = __expf(-d);
            }
}

// ------------------------------------------------------------------ launch ---
extern "C" void kernel_launch(void* const* d_in, const int* in_sizes, int n_in,
                              void* d_out, int out_size, void* d_ws, size_t ws_size,
                              hipStream_t stream)
{
    const float* x  = (const float*)d_in[0];
    const float* x1 = (const float*)d_in[1];
    float* out = (float*)d_out;

    const size_t f8_bytes  = (size_t)NROWS * DIMK;                       // 4 MB each
    const size_t need_full = 2 * f8_bytes + 2 * (size_t)NROWS * sizeof(float);

    dim3 gridG(NROWS / BM, NROWS / BN);   // 64 x 64 blocks

    if (ws_size >= need_full) {
        uint8_t* xf   = (uint8_t*)d_ws;
        uint8_t* x1f  = xf + f8_bytes;
        float*   xsq  = (float*)((char*)d_ws + 2 * f8_bytes);
        float*   x1sq = xsq + NROWS;
        precast_fp8<<<dim3(NROWS / 4, 2), 256, 0, stream>>>(x, x1, xf, x1f, xsq, x1sq);
        rbf_mfma_mxfp8<<<gridG, 256, 0, stream>>>(xf, x1f, xsq, x1sq, out);
    } else {
        float* xsq  = (float*)d_ws;       // 64 KB fallback
        float* x1sq = xsq + NROWS;
        norms_only<<<dim3(NROWS, 2), 256, 0, stream>>>(x, x1, xsq, x1sq);
        rbf_mfma_inline<<<gridG, 256, 0, stream>>>(x, x1, xsq, x1sq, out);
    }
}